// Round 4
// baseline (1621.587 us; speedup 1.0000x reference)
//
#include <hip/hip_runtime.h>
#include <hip/hip_cooperative_groups.h>
#include <float.h>
#include <math.h>

namespace cg = cooperative_groups;

#define NB 1024      // number of graphs B
#define NSTEPS 5
#define SPLIT 4      // fallback path only

__device__ __forceinline__ float sigmoidf_(float x) {
    return 1.0f / (1.0f + __expf(-x));
}

// ======================= cooperative mega-kernel =======================
union SharedU {
    struct { float qs[8][128]; float gates[8][256]; } lstm;   // 12 KB
    struct { float lm[4]; float ls[4]; float lr[4][64]; } attn;
    struct { float qs[128]; float hid[256]; } mlp;
};

__global__ __launch_bounds__(256, 4) void mega_kernel(
    const float* __restrict__ x, const int* __restrict__ batch, int N,
    const float* __restrict__ W_ih, const float* __restrict__ W_hh,
    const float* __restrict__ b_ih, const float* __restrict__ b_hh,
    const float* __restrict__ W1, const float* __restrict__ b1,
    const float* __restrict__ W2, const float* __restrict__ b2,
    float* __restrict__ h, float* __restrict__ c, float* __restrict__ rbuf,
    int* __restrict__ seg, float* __restrict__ out)
{
    cg::grid_group grid = cg::this_grid();
    __shared__ SharedU sh;
    const int blk = blockIdx.x, tid = threadIdx.x;

    // ---- phase 0: seg-bounds scan (blocks 128..1023) || LSTM step 0 (blocks 0..127)
    if (blk >= 128) {
        for (int i = (blk - 128) * 256 + tid; i < N; i += 896 * 256) {
            int b = batch[i];
            if (i == 0) { for (int j = 0; j <= b; ++j) seg[j] = 0; }
            else { int pb = batch[i - 1]; for (int j = pb + 1; j <= b; ++j) seg[j] = i; }
            if (i == N - 1) { for (int j = b + 1; j <= NB; ++j) seg[j] = N; }
        }
    } else {
        // step 0: q_star = 0, h = 0 -> gates = b_ih + b_hh (identical for all graphs)
        int g0 = blk * 8;
        sh.lstm.gates[0][tid] = b_ih[tid] + b_hh[tid];
        __syncthreads();
        for (int idx = tid; idx < 8 * 64; idx += 256) {
            int g = idx >> 6, jj = idx & 63;
            int gb = g0 + g;
            float ig = sigmoidf_(sh.lstm.gates[0][jj]);
            float fg = sigmoidf_(sh.lstm.gates[0][jj + 64]);
            float gg = tanhf(sh.lstm.gates[0][jj + 128]);
            float og = sigmoidf_(sh.lstm.gates[0][jj + 192]);
            (void)fg;
            float cn = ig * gg;
            float hn = og * tanhf(cn);
            c[gb * 64 + jj] = cn;
            h[gb * 64 + jj] = hn;
        }
    }
    grid.sync();

    for (int step = 0; ; ++step) {
        // ---------- attention: all 1024 blocks, block = graph ----------
        {
            const int b = blk;
            const int s = seg[b], e = seg[b + 1];
            const int lane = tid & 63;
            const int wave = tid >> 6;
            const int fc = lane & 15;      // feature chunk (4 floats)
            const int grp = lane >> 4;     // node subgroup 0..3

            float4 q4 = *(const float4*)(h + b * 64 + fc * 4);

            float m = -FLT_MAX, sum = 0.0f;
            float4 r4 = make_float4(0.0f, 0.0f, 0.0f, 0.0f);

            const int maxidx4 = e * 16 - 1;
            for (int base = s + wave * 16; base < e; base += 64) {
#pragma unroll
                for (int t = 0; t < 4; ++t) {
                    int node = base + t * 4 + grp;
                    int idx4 = base * 16 + t * 64 + lane;
                    idx4 = min(idx4, maxidx4);
                    float4 xv = *(const float4*)(x + (size_t)idx4 * 4);

                    float d = xv.x * q4.x;
                    d = fmaf(xv.y, q4.y, d);
                    d = fmaf(xv.z, q4.z, d);
                    d = fmaf(xv.w, q4.w, d);
                    d += __shfl_xor(d, 1);
                    d += __shfl_xor(d, 2);
                    d += __shfl_xor(d, 4);
                    d += __shfl_xor(d, 8);

                    bool valid = node < e;
                    float eeff = valid ? d : -FLT_MAX;
                    float nm = fmaxf(m, eeff);
                    float sc = __expf(m - nm);
                    float w = valid ? __expf(eeff - nm) : 0.0f;
                    sum = fmaf(sum, sc, w);
                    r4.x = fmaf(r4.x, sc, w * xv.x);
                    r4.y = fmaf(r4.y, sc, w * xv.y);
                    r4.z = fmaf(r4.z, sc, w * xv.z);
                    r4.w = fmaf(r4.w, sc, w * xv.w);
                    m = nm;
                }
            }

            // merge across the 4 node-subgroups
#pragma unroll
            for (int off = 16; off < 64; off <<= 1) {
                float om = __shfl_xor(m, off);
                float os = __shfl_xor(sum, off);
                float ox = __shfl_xor(r4.x, off);
                float oy = __shfl_xor(r4.y, off);
                float oz = __shfl_xor(r4.z, off);
                float ow = __shfl_xor(r4.w, off);
                float nm = fmaxf(m, om);
                float s1 = __expf(m - nm);
                float s2 = __expf(om - nm);
                sum = sum * s1 + os * s2;
                r4.x = r4.x * s1 + ox * s2;
                r4.y = r4.y * s1 + oy * s2;
                r4.z = r4.z * s1 + oz * s2;
                r4.w = r4.w * s1 + ow * s2;
                m = nm;
            }

            __syncthreads();   // LDS union handoff
            if (lane < 16) {
                if (lane == 0) { sh.attn.lm[wave] = m; sh.attn.ls[wave] = sum; }
                *(float4*)&sh.attn.lr[wave][lane * 4] = r4;
            }
            __syncthreads();
            if (tid < 64) {
                float M = fmaxf(fmaxf(sh.attn.lm[0], sh.attn.lm[1]),
                                fmaxf(sh.attn.lm[2], sh.attn.lm[3]));
                float w0 = __expf(sh.attn.lm[0] - M), w1 = __expf(sh.attn.lm[1] - M);
                float w2 = __expf(sh.attn.lm[2] - M), w3 = __expf(sh.attn.lm[3] - M);
                float S = sh.attn.ls[0] * w0 + sh.attn.ls[1] * w1
                        + sh.attn.ls[2] * w2 + sh.attn.ls[3] * w3;
                float rf = sh.attn.lr[0][tid] * w0 + sh.attn.lr[1][tid] * w1
                         + sh.attn.lr[2][tid] * w2 + sh.attn.lr[3][tid] * w3;
                rbuf[b * 64 + tid] = rf / fmaxf(S, 1e-16f);   // normalized r
            }
        }
        if (step == NSTEPS - 1) break;
        grid.sync();

        // ---------- LSTM: blocks 0..127, 8 graphs each ----------
        if (blk < 128) {
            int g0 = blk * 8;
            for (int idx = tid; idx < 8 * 64; idx += 256) {
                int g = idx >> 6, k = idx & 63;
                sh.lstm.qs[g][k] = h[(g0 + g) * 64 + k];
                sh.lstm.qs[g][64 + k] = rbuf[(g0 + g) * 64 + k];
            }
            __syncthreads();

            float acc[8];
            float bias = b_ih[tid] + b_hh[tid];
#pragma unroll
            for (int g = 0; g < 8; ++g) acc[g] = bias;
            const float4* wih = (const float4*)(W_ih + tid * 128);
#pragma unroll 4
            for (int k4 = 0; k4 < 32; ++k4) {
                float4 w = wih[k4];
#pragma unroll
                for (int g = 0; g < 8; ++g) {
                    acc[g] = fmaf(w.x, sh.lstm.qs[g][k4 * 4 + 0], acc[g]);
                    acc[g] = fmaf(w.y, sh.lstm.qs[g][k4 * 4 + 1], acc[g]);
                    acc[g] = fmaf(w.z, sh.lstm.qs[g][k4 * 4 + 2], acc[g]);
                    acc[g] = fmaf(w.w, sh.lstm.qs[g][k4 * 4 + 3], acc[g]);
                }
            }
            const float4* whh = (const float4*)(W_hh + tid * 64);
#pragma unroll 4
            for (int k4 = 0; k4 < 16; ++k4) {
                float4 w = whh[k4];
#pragma unroll
                for (int g = 0; g < 8; ++g) {
                    acc[g] = fmaf(w.x, sh.lstm.qs[g][k4 * 4 + 0], acc[g]);
                    acc[g] = fmaf(w.y, sh.lstm.qs[g][k4 * 4 + 1], acc[g]);
                    acc[g] = fmaf(w.z, sh.lstm.qs[g][k4 * 4 + 2], acc[g]);
                    acc[g] = fmaf(w.w, sh.lstm.qs[g][k4 * 4 + 3], acc[g]);
                }
            }
#pragma unroll
            for (int g = 0; g < 8; ++g) sh.lstm.gates[g][tid] = acc[g];
            __syncthreads();

            for (int idx = tid; idx < 8 * 64; idx += 256) {
                int g = idx >> 6, jj = idx & 63;
                int gb = g0 + g;
                float ig = sigmoidf_(sh.lstm.gates[g][jj]);
                float fg = sigmoidf_(sh.lstm.gates[g][jj + 64]);
                float gg = tanhf(sh.lstm.gates[g][jj + 128]);
                float og = sigmoidf_(sh.lstm.gates[g][jj + 192]);
                float cn = fmaf(fg, c[gb * 64 + jj], ig * gg);
                float hn = og * tanhf(cn);
                c[gb * 64 + jj] = cn;
                h[gb * 64 + jj] = hn;
            }
        }
        grid.sync();
    }

    // ---------- MLP: block = graph ----------
    __syncthreads();
    {
        const int b = blk;
        if (tid < 64) sh.mlp.qs[tid] = h[b * 64 + tid];
        else if (tid < 128) sh.mlp.qs[tid] = rbuf[b * 64 + (tid - 64)];
        __syncthreads();
        float acc = b1[tid];
        const float4* w = (const float4*)(W1 + tid * 128);
#pragma unroll 4
        for (int k4 = 0; k4 < 32; ++k4) {
            float4 ww = w[k4];
            acc = fmaf(ww.x, sh.mlp.qs[k4 * 4 + 0], acc);
            acc = fmaf(ww.y, sh.mlp.qs[k4 * 4 + 1], acc);
            acc = fmaf(ww.z, sh.mlp.qs[k4 * 4 + 2], acc);
            acc = fmaf(ww.w, sh.mlp.qs[k4 * 4 + 3], acc);
        }
        sh.mlp.hid[tid] = fmaxf(acc, 0.0f);
        __syncthreads();
        if (tid < 128) {
            float acc2 = b2[tid];
            const float4* w2 = (const float4*)(W2 + tid * 256);
#pragma unroll 4
            for (int k4 = 0; k4 < 64; ++k4) {
                float4 ww = w2[k4];
                acc2 = fmaf(ww.x, sh.mlp.hid[k4 * 4 + 0], acc2);
                acc2 = fmaf(ww.y, sh.mlp.hid[k4 * 4 + 1], acc2);
                acc2 = fmaf(ww.z, sh.mlp.hid[k4 * 4 + 2], acc2);
                acc2 = fmaf(ww.w, sh.mlp.hid[k4 * 4 + 3], acc2);
            }
            out[b * 128 + tid] = acc2;
        }
    }
}

// ======================= fallback path (R3, 12 launches) =======================
__global__ void seg_bounds_kernel(const int* __restrict__ batch,
                                  int* __restrict__ seg_start, int n) {
    int i = blockIdx.x * blockDim.x + threadIdx.x;
    if (i >= n) return;
    int b = batch[i];
    if (i == 0) { for (int j = 0; j <= b; ++j) seg_start[j] = 0; }
    else { int pb = batch[i - 1]; for (int j = pb + 1; j <= b; ++j) seg_start[j] = i; }
    if (i == n - 1) { for (int j = b + 1; j <= NB; ++j) seg_start[j] = n; }
}

__global__ void lstm_kernel_fb(const float* __restrict__ W_ih, const float* __restrict__ W_hh,
                               const float* __restrict__ b_ih, const float* __restrict__ b_hh,
                               const float* __restrict__ rbuf,
                               float* __restrict__ h, float* __restrict__ c, int first) {
    const int G = 8;
    int g0 = blockIdx.x * G;
    __shared__ float s_qs[G][128];
    __shared__ float s_gates[G][256];
    int tid = threadIdx.x;
    if (!first) {
        for (int idx = tid; idx < G * 64; idx += 256) {
            int g = idx >> 6, k = idx & 63;
            s_qs[g][k] = h[(g0 + g) * 64 + k];
            s_qs[g][64 + k] = rbuf[(g0 + g) * 64 + k];
        }
        __syncthreads();
    }
    int j = tid;
    float acc[G];
    float bias = b_ih[j] + b_hh[j];
#pragma unroll
    for (int g = 0; g < G; ++g) acc[g] = bias;
    if (!first) {
        const float4* wih = (const float4*)(W_ih + j * 128);
#pragma unroll 4
        for (int k4 = 0; k4 < 32; ++k4) {
            float4 w = wih[k4];
#pragma unroll
            for (int g = 0; g < G; ++g) {
                acc[g] = fmaf(w.x, s_qs[g][k4 * 4 + 0], acc[g]);
                acc[g] = fmaf(w.y, s_qs[g][k4 * 4 + 1], acc[g]);
                acc[g] = fmaf(w.z, s_qs[g][k4 * 4 + 2], acc[g]);
                acc[g] = fmaf(w.w, s_qs[g][k4 * 4 + 3], acc[g]);
            }
        }
        const float4* whh = (const float4*)(W_hh + j * 64);
#pragma unroll 4
        for (int k4 = 0; k4 < 16; ++k4) {
            float4 w = whh[k4];
#pragma unroll
            for (int g = 0; g < G; ++g) {
                acc[g] = fmaf(w.x, s_qs[g][k4 * 4 + 0], acc[g]);
                acc[g] = fmaf(w.y, s_qs[g][k4 * 4 + 1], acc[g]);
                acc[g] = fmaf(w.z, s_qs[g][k4 * 4 + 2], acc[g]);
                acc[g] = fmaf(w.w, s_qs[g][k4 * 4 + 3], acc[g]);
            }
        }
    }
#pragma unroll
    for (int g = 0; g < G; ++g) s_gates[g][j] = acc[g];
    __syncthreads();
    for (int idx = tid; idx < G * 64; idx += 256) {
        int g = idx >> 6, jj = idx & 63;
        int gb = g0 + g;
        float ig = sigmoidf_(s_gates[g][jj]);
        float fg = sigmoidf_(s_gates[g][jj + 64]);
        float gg = tanhf(s_gates[g][jj + 128]);
        float og = sigmoidf_(s_gates[g][jj + 192]);
        float cprev = first ? 0.0f : c[gb * 64 + jj];
        float cn = fmaf(fg, cprev, ig * gg);
        float hn = og * tanhf(cn);
        c[gb * 64 + jj] = cn;
        h[gb * 64 + jj] = hn;
    }
}

__global__ __launch_bounds__(256) void attn_kernel_fb(const float* __restrict__ x,
                                                      const int* __restrict__ seg_start,
                                                      const float* __restrict__ h,
                                                      float* __restrict__ rbuf) {
    int b = blockIdx.x;
    int s = seg_start[b], e = seg_start[b + 1];
    int tid = threadIdx.x;
    int lane = tid & 63;
    int wave = tid >> 6;
    int fc = lane & 15;
    int grp = lane >> 4;
    float4 q4 = *(const float4*)(h + b * 64 + fc * 4);
    float m = -FLT_MAX, sum = 0.0f;
    float4 r4 = make_float4(0.0f, 0.0f, 0.0f, 0.0f);
    const int maxidx4 = e * 16 - 1;
    for (int base = s + wave * 16; base < e; base += 64) {
#pragma unroll
        for (int t = 0; t < 4; ++t) {
            int node = base + t * 4 + grp;
            int idx4 = base * 16 + t * 64 + lane;
            idx4 = min(idx4, maxidx4);
            float4 xv = *(const float4*)(x + (size_t)idx4 * 4);
            float d = xv.x * q4.x;
            d = fmaf(xv.y, q4.y, d);
            d = fmaf(xv.z, q4.z, d);
            d = fmaf(xv.w, q4.w, d);
            d += __shfl_xor(d, 1);
            d += __shfl_xor(d, 2);
            d += __shfl_xor(d, 4);
            d += __shfl_xor(d, 8);
            bool valid = node < e;
            float eeff = valid ? d : -FLT_MAX;
            float nm = fmaxf(m, eeff);
            float sc = __expf(m - nm);
            float w = valid ? __expf(eeff - nm) : 0.0f;
            sum = fmaf(sum, sc, w);
            r4.x = fmaf(r4.x, sc, w * xv.x);
            r4.y = fmaf(r4.y, sc, w * xv.y);
            r4.z = fmaf(r4.z, sc, w * xv.z);
            r4.w = fmaf(r4.w, sc, w * xv.w);
            m = nm;
        }
    }
#pragma unroll
    for (int off = 16; off < 64; off <<= 1) {
        float om = __shfl_xor(m, off);
        float os = __shfl_xor(sum, off);
        float ox = __shfl_xor(r4.x, off);
        float oy = __shfl_xor(r4.y, off);
        float oz = __shfl_xor(r4.z, off);
        float ow = __shfl_xor(r4.w, off);
        float nm = fmaxf(m, om);
        float s1 = __expf(m - nm);
        float s2 = __expf(om - nm);
        sum = sum * s1 + os * s2;
        r4.x = r4.x * s1 + ox * s2;
        r4.y = r4.y * s1 + oy * s2;
        r4.z = r4.z * s1 + oz * s2;
        r4.w = r4.w * s1 + ow * s2;
        m = nm;
    }
    __shared__ float lm[4], ls[4], lr[4][64];
    if (lane < 16) {
        if (lane == 0) { lm[wave] = m; ls[wave] = sum; }
        *(float4*)&lr[wave][lane * 4] = r4;
    }
    __syncthreads();
    if (tid < 64) {
        float M = fmaxf(fmaxf(lm[0], lm[1]), fmaxf(lm[2], lm[3]));
        float w0 = __expf(lm[0] - M), w1 = __expf(lm[1] - M);
        float w2 = __expf(lm[2] - M), w3 = __expf(lm[3] - M);
        float S = ls[0] * w0 + ls[1] * w1 + ls[2] * w2 + ls[3] * w3;
        float rf = lr[0][tid] * w0 + lr[1][tid] * w1 + lr[2][tid] * w2 + lr[3][tid] * w3;
        rbuf[b * 64 + tid] = rf / fmaxf(S, 1e-16f);
    }
}

__global__ void mlp_kernel_fb(const float* __restrict__ h, const float* __restrict__ rbuf,
                              const float* __restrict__ W1, const float* __restrict__ b1,
                              const float* __restrict__ W2, const float* __restrict__ b2,
                              float* __restrict__ out) {
    int b = blockIdx.x;
    __shared__ float qs[128];
    __shared__ float hid[256];
    int tid = threadIdx.x;
    if (tid < 64) qs[tid] = h[b * 64 + tid];
    else if (tid < 128) qs[tid] = rbuf[b * 64 + (tid - 64)];
    __syncthreads();
    float acc = b1[tid];
    const float4* w = (const float4*)(W1 + tid * 128);
#pragma unroll 4
    for (int k4 = 0; k4 < 32; ++k4) {
        float4 ww = w[k4];
        acc = fmaf(ww.x, qs[k4 * 4 + 0], acc);
        acc = fmaf(ww.y, qs[k4 * 4 + 1], acc);
        acc = fmaf(ww.z, qs[k4 * 4 + 2], acc);
        acc = fmaf(ww.w, qs[k4 * 4 + 3], acc);
    }
    hid[tid] = fmaxf(acc, 0.0f);
    __syncthreads();
    if (tid < 128) {
        float acc2 = b2[tid];
        const float4* w2 = (const float4*)(W2 + tid * 256);
#pragma unroll 4
        for (int k4 = 0; k4 < 64; ++k4) {
            float4 ww = w2[k4];
            acc2 = fmaf(ww.x, hid[k4 * 4 + 0], acc2);
            acc2 = fmaf(ww.y, hid[k4 * 4 + 1], acc2);
            acc2 = fmaf(ww.z, hid[k4 * 4 + 2], acc2);
            acc2 = fmaf(ww.w, hid[k4 * 4 + 3], acc2);
        }
        out[b * 128 + tid] = acc2;
    }
}

extern "C" void kernel_launch(void* const* d_in, const int* in_sizes, int n_in,
                              void* d_out, int out_size, void* d_ws, size_t ws_size,
                              hipStream_t stream) {
    const float* x    = (const float*)d_in[0];   // [N,64]
    const int*   batch= (const int*)d_in[1];     // [N] sorted (harness converts to int32)
    const float* W_ih = (const float*)d_in[2];   // [256,128]
    const float* W_hh = (const float*)d_in[3];   // [256,64]
    const float* b_ih = (const float*)d_in[4];
    const float* b_hh = (const float*)d_in[5];
    const float* W1   = (const float*)d_in[6];   // [256,128]
    const float* b1   = (const float*)d_in[7];
    const float* W2   = (const float*)d_in[8];   // [128,256]
    const float* b2   = (const float*)d_in[9];
    float* out = (float*)d_out;
    int N = in_sizes[1];

    // workspace layout
    float* h    = (float*)d_ws;                  // NB*64
    float* c    = h + NB * 64;                   // NB*64
    float* rbuf = c + NB * 64;                   // NB*64
    int*   seg  = (int*)(rbuf + NB * 64);        // NB+8

    void* args[] = {
        (void*)&x, (void*)&batch, (void*)&N,
        (void*)&W_ih, (void*)&W_hh, (void*)&b_ih, (void*)&b_hh,
        (void*)&W1, (void*)&b1, (void*)&W2, (void*)&b2,
        (void*)&h, (void*)&c, (void*)&rbuf, (void*)&seg, (void*)&out
    };
    hipError_t err = hipLaunchCooperativeKernel((void*)mega_kernel, dim3(NB), dim3(256),
                                                args, 0, stream);
    if (err != hipSuccess) {
        // deterministic fallback: 12-launch pipeline (R3 structure, SPLIT=1)
        seg_bounds_kernel<<<(N + 255) / 256, 256, 0, stream>>>(batch, seg, N);
        for (int step = 0; step < NSTEPS; ++step) {
            lstm_kernel_fb<<<NB / 8, 256, 0, stream>>>(W_ih, W_hh, b_ih, b_hh,
                                                       rbuf, h, c, step == 0 ? 1 : 0);
            attn_kernel_fb<<<NB, 256, 0, stream>>>(x, seg, h, rbuf);
        }
        mlp_kernel_fb<<<NB, 256, 0, stream>>>(h, rbuf, W1, b1, W2, b2, out);
    }
}

// Round 5
// 626.890 us; speedup vs baseline: 2.5867x; 2.5867x over previous
//
#include <hip/hip_runtime.h>
#include <float.h>
#include <math.h>

#define NB 1024      // number of graphs B
#define NSTEPS 5

__device__ __forceinline__ float sigmoidf_(float x) {
    return 1.0f / (1.0f + __expf(-x));
}

// ---------------- segment boundaries from sorted batch ----------------
__global__ void seg_bounds_kernel(const int* __restrict__ batch,
                                  int* __restrict__ seg_start, int n) {
    int i = blockIdx.x * blockDim.x + threadIdx.x;
    if (i >= n) return;
    int b = batch[i];
    if (i == 0) { for (int j = 0; j <= b; ++j) seg_start[j] = 0; }
    else { int pb = batch[i - 1]; for (int j = pb + 1; j <= b; ++j) seg_start[j] = i; }
    if (i == n - 1) { for (int j = b + 1; j <= NB; ++j) seg_start[j] = n; }
}

// ---------------- LSTM cell (8 graphs/block) ----------------
__global__ void lstm_kernel(const float* __restrict__ W_ih, const float* __restrict__ W_hh,
                            const float* __restrict__ b_ih, const float* __restrict__ b_hh,
                            const float* __restrict__ rbuf,   // [NB,64] normalized r (prev step)
                            float* __restrict__ h, float* __restrict__ c, int first) {
    const int G = 8;
    int g0 = blockIdx.x * G;
    __shared__ float s_qs[G][128];
    __shared__ float s_gates[G][256];
    int tid = threadIdx.x;
    if (!first) {
        for (int idx = tid; idx < G * 64; idx += 256) {
            int g = idx >> 6, k = idx & 63;
            s_qs[g][k] = h[(g0 + g) * 64 + k];
            s_qs[g][64 + k] = rbuf[(g0 + g) * 64 + k];
        }
        __syncthreads();
    }
    int j = tid;
    float acc[G];
    float bias = b_ih[j] + b_hh[j];
#pragma unroll
    for (int g = 0; g < G; ++g) acc[g] = bias;
    if (!first) {
        const float4* wih = (const float4*)(W_ih + j * 128);
#pragma unroll 4
        for (int k4 = 0; k4 < 32; ++k4) {
            float4 w = wih[k4];
#pragma unroll
            for (int g = 0; g < G; ++g) {
                acc[g] = fmaf(w.x, s_qs[g][k4 * 4 + 0], acc[g]);
                acc[g] = fmaf(w.y, s_qs[g][k4 * 4 + 1], acc[g]);
                acc[g] = fmaf(w.z, s_qs[g][k4 * 4 + 2], acc[g]);
                acc[g] = fmaf(w.w, s_qs[g][k4 * 4 + 3], acc[g]);
            }
        }
        const float4* whh = (const float4*)(W_hh + j * 64);
#pragma unroll 4
        for (int k4 = 0; k4 < 16; ++k4) {
            float4 w = whh[k4];
#pragma unroll
            for (int g = 0; g < G; ++g) {
                acc[g] = fmaf(w.x, s_qs[g][k4 * 4 + 0], acc[g]);
                acc[g] = fmaf(w.y, s_qs[g][k4 * 4 + 1], acc[g]);
                acc[g] = fmaf(w.z, s_qs[g][k4 * 4 + 2], acc[g]);
                acc[g] = fmaf(w.w, s_qs[g][k4 * 4 + 3], acc[g]);
            }
        }
    }
#pragma unroll
    for (int g = 0; g < G; ++g) s_gates[g][j] = acc[g];
    __syncthreads();
    for (int idx = tid; idx < G * 64; idx += 256) {
        int g = idx >> 6, jj = idx & 63;
        int gb = g0 + g;
        float ig = sigmoidf_(s_gates[g][jj]);
        float fg = sigmoidf_(s_gates[g][jj + 64]);
        float gg = tanhf(s_gates[g][jj + 128]);
        float og = sigmoidf_(s_gates[g][jj + 192]);
        float cprev = first ? 0.0f : c[gb * 64 + jj];
        float cn = fmaf(fg, cprev, ig * gg);
        float hn = og * tanhf(cn);
        c[gb * 64 + jj] = cn;
        h[gb * 64 + jj] = hn;
    }
}

// ---------------- fused segment attention: online softmax, register double-buffered ----------------
// One block per graph; 4 waves; each wave handles 32 nodes/stage (stride 128), prefetching the
// next stage's 8x1KB coalesced float4 loads before consuming the current stage. Lane layout:
// fc = lane&15 -> feature chunk (4 floats), grp = lane>>4 -> node-subgroup; 4 nodes per t-chunk.
__global__ __launch_bounds__(256) void attn_kernel(const float* __restrict__ x,
                                                   const int* __restrict__ seg_start,
                                                   const float* __restrict__ h,
                                                   float* __restrict__ rbuf) {
    int b = blockIdx.x;
    int s = seg_start[b], e = seg_start[b + 1];
    int tid = threadIdx.x;
    int lane = tid & 63;
    int wave = tid >> 6;
    int fc = lane & 15;
    int grp = lane >> 4;

    float4 q4 = *(const float4*)(h + b * 64 + fc * 4);

    float m = -FLT_MAX, sum = 0.0f;
    float4 r4 = make_float4(0.0f, 0.0f, 0.0f, 0.0f);

    const int maxidx4 = e * 16 - 1;
    int pos = s + wave * 32;

    if (pos < e) {                      // wave-uniform
        float4 cur[8];
#pragma unroll
        for (int t = 0; t < 8; ++t) {
            int idx4 = min(pos * 16 + t * 64 + lane, maxidx4);
            cur[t] = *(const float4*)(x + (size_t)idx4 * 4);
        }
        while (true) {
            int pos2 = pos + 128;
            bool more = (pos2 < e);      // wave-uniform
            float4 nxt[8];
            if (more) {
#pragma unroll
                for (int t = 0; t < 8; ++t) {
                    int idx4 = min(pos2 * 16 + t * 64 + lane, maxidx4);
                    nxt[t] = *(const float4*)(x + (size_t)idx4 * 4);
                }
            }
            // consume current stage while nxt loads are in flight
#pragma unroll
            for (int t = 0; t < 8; ++t) {
                int node = pos + t * 4 + grp;
                float4 xv = cur[t];
                float d = xv.x * q4.x;
                d = fmaf(xv.y, q4.y, d);
                d = fmaf(xv.z, q4.z, d);
                d = fmaf(xv.w, q4.w, d);
                d += __shfl_xor(d, 1);
                d += __shfl_xor(d, 2);
                d += __shfl_xor(d, 4);
                d += __shfl_xor(d, 8);

                bool valid = node < e;
                float eeff = valid ? d : -FLT_MAX;
                float nm = fmaxf(m, eeff);
                float sc = __expf(m - nm);
                float w = valid ? __expf(eeff - nm) : 0.0f;
                sum = fmaf(sum, sc, w);
                r4.x = fmaf(r4.x, sc, w * xv.x);
                r4.y = fmaf(r4.y, sc, w * xv.y);
                r4.z = fmaf(r4.z, sc, w * xv.z);
                r4.w = fmaf(r4.w, sc, w * xv.w);
                m = nm;
            }
            if (!more) break;
            pos = pos2;
#pragma unroll
            for (int t = 0; t < 8; ++t) cur[t] = nxt[t];
        }
    }

    // merge across the 4 node-subgroups (lanes with equal fc share feature chunk)
#pragma unroll
    for (int off = 16; off < 64; off <<= 1) {
        float om = __shfl_xor(m, off);
        float os = __shfl_xor(sum, off);
        float ox = __shfl_xor(r4.x, off);
        float oy = __shfl_xor(r4.y, off);
        float oz = __shfl_xor(r4.z, off);
        float ow = __shfl_xor(r4.w, off);
        float nm = fmaxf(m, om);
        float s1 = __expf(m - nm);
        float s2 = __expf(om - nm);
        sum = sum * s1 + os * s2;
        r4.x = r4.x * s1 + ox * s2;
        r4.y = r4.y * s1 + oy * s2;
        r4.z = r4.z * s1 + oz * s2;
        r4.w = r4.w * s1 + ow * s2;
        m = nm;
    }

    // cross-wave merge via LDS, then write normalized r
    __shared__ float lm[4], ls[4], lr[4][64];
    if (lane < 16) {
        if (lane == 0) { lm[wave] = m; ls[wave] = sum; }
        *(float4*)&lr[wave][lane * 4] = r4;
    }
    __syncthreads();
    if (tid < 64) {
        float M = fmaxf(fmaxf(lm[0], lm[1]), fmaxf(lm[2], lm[3]));
        float w0 = __expf(lm[0] - M), w1 = __expf(lm[1] - M);
        float w2 = __expf(lm[2] - M), w3 = __expf(lm[3] - M);
        float S = ls[0] * w0 + ls[1] * w1 + ls[2] * w2 + ls[3] * w3;
        float rf = lr[0][tid] * w0 + lr[1][tid] * w1 + lr[2][tid] * w2 + lr[3][tid] * w3;
        rbuf[b * 64 + tid] = rf / fmaxf(S, 1e-16f);
    }
}

// ---------------- final MLP ----------------
__global__ void mlp_kernel(const float* __restrict__ h, const float* __restrict__ rbuf,
                           const float* __restrict__ W1, const float* __restrict__ b1,
                           const float* __restrict__ W2, const float* __restrict__ b2,
                           float* __restrict__ out) {
    int b = blockIdx.x;
    __shared__ float qs[128];
    __shared__ float hid[256];
    int tid = threadIdx.x;
    if (tid < 64) qs[tid] = h[b * 64 + tid];
    else if (tid < 128) qs[tid] = rbuf[b * 64 + (tid - 64)];
    __syncthreads();
    float acc = b1[tid];
    const float4* w = (const float4*)(W1 + tid * 128);
#pragma unroll 4
    for (int k4 = 0; k4 < 32; ++k4) {
        float4 ww = w[k4];
        acc = fmaf(ww.x, qs[k4 * 4 + 0], acc);
        acc = fmaf(ww.y, qs[k4 * 4 + 1], acc);
        acc = fmaf(ww.z, qs[k4 * 4 + 2], acc);
        acc = fmaf(ww.w, qs[k4 * 4 + 3], acc);
    }
    hid[tid] = fmaxf(acc, 0.0f);
    __syncthreads();
    if (tid < 128) {
        float acc2 = b2[tid];
        const float4* w2 = (const float4*)(W2 + tid * 256);
#pragma unroll 4
        for (int k4 = 0; k4 < 64; ++k4) {
            float4 ww = w2[k4];
            acc2 = fmaf(ww.x, hid[k4 * 4 + 0], acc2);
            acc2 = fmaf(ww.y, hid[k4 * 4 + 1], acc2);
            acc2 = fmaf(ww.z, hid[k4 * 4 + 2], acc2);
            acc2 = fmaf(ww.w, hid[k4 * 4 + 3], acc2);
        }
        out[b * 128 + tid] = acc2;
    }
}

extern "C" void kernel_launch(void* const* d_in, const int* in_sizes, int n_in,
                              void* d_out, int out_size, void* d_ws, size_t ws_size,
                              hipStream_t stream) {
    const float* x    = (const float*)d_in[0];   // [N,64]
    const int*   batch= (const int*)d_in[1];     // [N] sorted
    const float* W_ih = (const float*)d_in[2];   // [256,128]
    const float* W_hh = (const float*)d_in[3];   // [256,64]
    const float* b_ih = (const float*)d_in[4];
    const float* b_hh = (const float*)d_in[5];
    const float* W1   = (const float*)d_in[6];   // [256,128]
    const float* b1   = (const float*)d_in[7];
    const float* W2   = (const float*)d_in[8];   // [128,256]
    const float* b2   = (const float*)d_in[9];
    float* out = (float*)d_out;
    int N = in_sizes[1];

    // workspace layout
    float* h    = (float*)d_ws;                  // NB*64
    float* c    = h + NB * 64;                   // NB*64
    float* rbuf = c + NB * 64;                   // NB*64
    int*   seg  = (int*)(rbuf + NB * 64);        // NB+8

    seg_bounds_kernel<<<(N + 255) / 256, 256, 0, stream>>>(batch, seg, N);
    for (int step = 0; step < NSTEPS; ++step) {
        lstm_kernel<<<NB / 8, 256, 0, stream>>>(W_ih, W_hh, b_ih, b_hh,
                                                rbuf, h, c, step == 0 ? 1 : 0);
        attn_kernel<<<NB, 256, 0, stream>>>(x, seg, h, rbuf);
    }
    mlp_kernel<<<NB, 256, 0, stream>>>(h, rbuf, W1, b1, W2, b2, out);
}